// Round 8
// baseline (713.988 us; speedup 1.0000x reference)
//
#include <hip/hip_runtime.h>
#include <hip/hip_bf16.h>
#include <hip/hip_cooperative_groups.h>

// Problem constants (from reference)
#define NN 50000
#define EE 800000
#define GG 64
#define RR 3
#define CC 10
#define RPL 16   // pooling replica count (contention spreading)
#define NBG 782  // gemm virtual blocks
#define NBS 1563 // scatter virtual blocks (2 edges/thread)
#define NV1 (NBG + NBS)
#define ND4 (NN / 4)
#define WTN (832 * 64 + 832)
#define RPN 16   // dst: edges per node per round
// r22: ONE cooperative mega-kernel (4 phases, grid.sync between) to kill
// the ~80us/iter inter-kernel overhead that never appears in any dispatch:
//   p0 zero+Wpack -> p1 {MFMA GEMM (64-wide B tiles) || edge scatter}
//   grid-strided -> p2 dst virtual blocks -> p3 head (first 64 blocks).
// Shared-mem union 20480B (=160KB/8) so all phases co-reside; grid size
// from occupancy query; r21 4-launch fallback if coop launch unsupported.
// LESSONS kept: no reg/DMA double-buffer in dst (r16/r19 regressed); direct
// scatter not two-phase (r20 regressed); u16 sorted; typed compact buckets;
// offline softmax; FiLM 1/cnt folded into gamma/beta.

typedef __attribute__((ext_vector_type(8))) short bf16x8;
typedef __attribute__((ext_vector_type(4))) float f32x4;
namespace cg = cooperative_groups;

__device__ inline float leaky02(float x) { return x > 0.f ? x : 0.2f * x; }

__device__ inline void atomicMaxFPos(float* addr, float v) {
  atomicMax((int*)addr, __float_as_int(v));   // non-negative floats only
}

__device__ inline unsigned short f2bf(float f) {
  __hip_bfloat16 b = __float2bfloat16(f);
  return *reinterpret_cast<unsigned short*>(&b);
}
__device__ inline float bf2f(unsigned short u) {
  return __uint_as_float(((unsigned int)u) << 16);   // exact widening
}

__device__ inline float wpack_val(int idx,
    const float* skip_film_W, const float* skip_W, const float* film_lin_W,
    const float* film_film_W, const float* gat_W) {
  int c = idx >> 6, k = idx & 63;
  if (c < 128)      return skip_film_W[k * 128 + c];
  if (c < 192)      return skip_W[k * 64 + (c - 128)];
  if (c < 384) { int cc = c - 192, r = cc >> 6, h = cc & 63;
                 return film_lin_W[(r * 64 + k) * 64 + h]; }
  if (c < 768) { int cc = c - 384, r = cc >> 7, j = cc & 127;
                 return film_film_W[(r * 64 + k) * 128 + j]; }
  return gat_W[k * 64 + (c - 768)];
}

// ======================= mega kernel (cooperative) =======================
__global__ __launch_bounds__(256) void mega_k(
    const float* __restrict__ X, const int* __restrict__ ei,
    const int* __restrict__ et, const int* __restrict__ gb,
    const float* __restrict__ skip_film_W, const float* __restrict__ skip_W,
    const float* __restrict__ film_lin_W, const float* __restrict__ film_film_W,
    const float* __restrict__ gat_W, const float* __restrict__ skip_film_b,
    const float* __restrict__ film_film_b, const float* __restrict__ att_src,
    const float* __restrict__ att_dst, const float* __restrict__ gat_b,
    const float* __restrict__ lin_W, const float* __restrict__ lin_b,
    const float* __restrict__ fc_W, const float* __restrict__ fc_b,
    unsigned short* __restrict__ XP, unsigned short* __restrict__ XR,
    unsigned short* __restrict__ Ybg, unsigned short* __restrict__ S0b,
    float* __restrict__ as_, float* __restrict__ ad_,
    unsigned short* __restrict__ Wt, float* __restrict__ bias,
    float* __restrict__ pmax, float* __restrict__ psum,
    int* __restrict__ gend, int* __restrict__ fill4,
    int* __restrict__ gstart, unsigned short* __restrict__ sorted,
    float* __restrict__ zbase, int zN4, float* __restrict__ out) {
  cg::grid_group grid = cg::this_grid();
  __shared__ __align__(16) unsigned char smem[20480];
  const int tid = threadIdx.x;
  const int bid = blockIdx.x;
  const int nb  = gridDim.x;
  const int gsz = nb * 256;

  // -------------------- phase 0: zero + W pack --------------------
  {
    float4 z4 = {0.f, 0.f, 0.f, 0.f};
    for (int i = bid * 256 + tid; i < zN4; i += gsz)
      reinterpret_cast<float4*>(zbase)[i] = z4;
    for (int idx = bid * 256 + tid; idx < WTN; idx += gsz) {
      if (idx >= 832 * 64) {
        int c = idx - 832 * 64;
        float bv = 0.f;
        if (c < 128) bv = skip_film_b[c];
        else if (c >= 384 && c < 768) bv = film_film_b[c - 384];
        bias[c] = bv;
      } else {
        Wt[idx] = f2bf(wpack_val(idx, skip_film_W, skip_W, film_lin_W,
                                 film_film_W, gat_W));
      }
    }
  }
  grid.sync();

  // -------------------- phase 1: GEMM || scatter --------------------
  {
    unsigned short (*As)[72] = (unsigned short(*)[72])smem;            // 9216B
    unsigned short (*Bs)[72] = (unsigned short(*)[72])(smem + 9216);   // 9216B
    for (int vb = bid; vb < NV1; vb += nb) {
      __syncthreads();                   // LDS reuse across virtual iters
      if (vb % 3 != 0) {
        // ---- edge scatter: 2 edges/thread, u16 stores ----
        int sb = vb - vb / 3 - 1;        // 0..NBS-1
        int e = sb * 512 + tid * 2;
        if (e < EE) {
          int2 s2 = *reinterpret_cast<const int2*>(ei + e);
          int2 d2 = *reinterpret_cast<const int2*>(ei + EE + e);
          int2 t2 = *reinterpret_cast<const int2*>(et + e);
          int slot = atomicAdd(&fill4[d2.x * 4 + t2.x], 1);
          if (slot < 32)
            sorted[(size_t)d2.x * 96 + t2.x * 32 + slot] = (unsigned short)s2.x;
          slot = atomicAdd(&fill4[d2.y * 4 + t2.y], 1);
          if (slot < 32)
            sorted[(size_t)d2.y * 96 + t2.y * 32 + slot] = (unsigned short)s2.y;
        }
        continue;
      }
      // ---- GEMM virtual block ----
      const int row0 = (vb / 3) * 64;
      {
        int r = tid >> 2, c0 = (tid & 3) * 16;
        int gr = row0 + r;
        ushort4 o0 = {0,0,0,0}, o1 = {0,0,0,0}, o2 = {0,0,0,0}, o3 = {0,0,0,0};
        if (gr < NN) {
          const float4* p = reinterpret_cast<const float4*>(X + (size_t)gr * 64 + c0);
          float4 v0 = p[0], v1 = p[1], v2 = p[2], v3 = p[3];
          o0 = {f2bf(v0.x), f2bf(v0.y), f2bf(v0.z), f2bf(v0.w)};
          o1 = {f2bf(v1.x), f2bf(v1.y), f2bf(v1.z), f2bf(v1.w)};
          o2 = {f2bf(v2.x), f2bf(v2.y), f2bf(v2.z), f2bf(v2.w)};
          o3 = {f2bf(v3.x), f2bf(v3.y), f2bf(v3.z), f2bf(v3.w)};
        }
        *reinterpret_cast<ushort4*>(&As[r][c0])      = o0;
        *reinterpret_cast<ushort4*>(&As[r][c0 + 4])  = o1;
        *reinterpret_cast<ushort4*>(&As[r][c0 + 8])  = o2;
        *reinterpret_cast<ushort4*>(&As[r][c0 + 12]) = o3;
      }
      __syncthreads();
      const int w = tid >> 6, lane = tid & 63;
      const int m = lane & 15, q = lane >> 4;
      bf16x8 a0 = *reinterpret_cast<const bf16x8*>(&As[16 * w + m][q * 8]);
      bf16x8 a1 = *reinterpret_cast<const bf16x8*>(&As[16 * w + m][32 + q * 8]);
      const int rbase = row0 + 16 * w + q * 4;
      f32x4 t0[8], t1[4], t6[4];

      for (int tile = 0; tile < 13; tile++) {
        __syncthreads();
        int col0 = tile * 64;
        {
          int c = tid >> 2, qq = (tid & 3) * 16;
          const uint4* p = reinterpret_cast<const uint4*>(
              Wt + (size_t)(col0 + c) * 64 + qq);
          uint4 v0 = p[0], v1 = p[1];
          *reinterpret_cast<uint4*>(&Bs[c][qq])     = v0;
          *reinterpret_cast<uint4*>(&Bs[c][qq + 8]) = v1;
        }
        __syncthreads();
        #pragma unroll
        for (int ct = 0; ct < 4; ct++) {
          bf16x8 b0 = *reinterpret_cast<const bf16x8*>(&Bs[ct * 16 + m][q * 8]);
          bf16x8 b1 = *reinterpret_cast<const bf16x8*>(&Bs[ct * 16 + m][32 + q * 8]);
          f32x4 acc = {0.f, 0.f, 0.f, 0.f};
          acc = __builtin_amdgcn_mfma_f32_16x16x32_bf16(a0, b0, acc, 0, 0, 0);
          acc = __builtin_amdgcn_mfma_f32_16x16x32_bf16(a1, b1, acc, 0, 0, 0);
          if (tile == 0) { t0[ct] = acc; continue; }     // fs beta
          if (tile == 1) { t0[4 + ct] = acc; continue; } // fs gamma
          if (tile == 2) { t1[ct] = acc; continue; }     // xs
          if (tile == 12) t6[ct] = acc;                  // xp
          int cm = ct * 16 + m;
          float bv = (tile >= 6 && tile <= 11) ? bias[col0 + cm] : 0.f;
          #pragma unroll
          for (int rg = 0; rg < 4; rg++) {
            int gr = rbase + rg;
            if (gr >= NN) continue;
            float v = acc[rg];
            if (tile <= 5) {             // 3,4,5: xr_t
              XR[((size_t)(tile - 3) * NN + gr) * 64 + cm] = f2bf(v);
            } else if (tile <= 11) {     // 6..11: beta/gamma
              Ybg[(size_t)gr * 384 + (tile - 6) * 64 + cm] = f2bf(v + bv);
            } else {                     // 12: xp
              XP[(size_t)gr * 64 + cm] = f2bf(v);
            }
          }
        }
      }

      // ---- fused post: all in-lane ----
      float pa[4] = {0.f, 0.f, 0.f, 0.f}, pd[4] = {0.f, 0.f, 0.f, 0.f};
      #pragma unroll
      for (int j = 0; j < 4; j++) {
        int h = 16 * j + m;
        float bb = bias[h];
        float bg = bias[64 + h];
        float asv = att_src[h];
        float adv = att_dst[h];
        #pragma unroll
        for (int rg = 0; rg < 4; rg++) {
          float so = fmaxf((t0[4 + j][rg] + bg) * t1[j][rg] + (t0[j][rg] + bb), 0.f);
          int gr = rbase + rg;
          if (gr < NN) S0b[(size_t)gr * 64 + h] = f2bf(so);
          pa[rg] += t6[j][rg] * asv;
          pd[rg] += t6[j][rg] * adv;
        }
      }
      #pragma unroll
      for (int ofs = 1; ofs < 16; ofs <<= 1) {
        #pragma unroll
        for (int rg = 0; rg < 4; rg++) {
          pa[rg] += __shfl_xor(pa[rg], ofs);
          pd[rg] += __shfl_xor(pd[rg], ofs);
        }
      }
      if (m == 0) {
        #pragma unroll
        for (int rg = 0; rg < 4; rg++) {
          int gr = rbase + rg;
          if (gr < NN) { as_[gr] = pa[rg]; ad_[gr] = pd[rg]; }
        }
      }
    }
  }
  __threadfence();
  grid.sync();

  // -------------------- phase 2: dst virtual blocks --------------------
  {
    unsigned short (*s_rows)[128] = (unsigned short(*)[128])smem;   // 16384B
    int   (*s_pk)[96] = (int(*)[96])(smem + 16384);                 // 1536B
    float (*s_w)[96]  = (float(*)[96])(smem + 17920);               // 1536B
    int   (*s_d)[4]   = (int(*)[4])(smem + 19456);                  // 64B
    int*   s_g        = (int*)(smem + 19520);                       // 16B
    float* s_ad       = (float*)(smem + 19536);                     // 16B
    float* s_val      = (float*)smem;                               // 2KB alias

    const int wid = tid >> 6, h = tid & 63;
    const int grp16 = tid >> 4, lane16 = tid & 15;

    for (int vb = bid; vb < ND4; vb += nb) {
      __syncthreads();                   // protect prev iter's LDS reads
      const int n0 = vb * 4;
      const int n  = n0 + wid;
      size_t rep = (size_t)(vb & (RPL - 1)) * GG * 128;
      float* pm = pmax + rep;
      float* ps = psum + rep;

      if (tid < 16) {
        int wd = tid >> 2, t = tid & 3;
        if (t < 3) {
          int d = fill4[(n0 + wd) * 4 + t];
          s_d[wd][t] = d > 32 ? 32 : d;
        } else {
          s_g[wd]  = gb[n0 + wd];
          s_ad[wd] = ad_[n0 + wd];
        }
      }
      __syncthreads();

      for (int i = tid; i < 512; i += 256) {
        int wd = i >> 7, s = i & 127;
        if (s < 96) {
          int tt = s >> 5, j = s & 31;
          if (j < s_d[wd][tt]) {
            int cidx = (tt == 0) ? j
                     : (tt == 1) ? s_d[wd][0] + j
                                 : s_d[wd][0] + s_d[wd][1] + j;
            int src = sorted[(size_t)(n0 + wd) * 96 + s];
            s_pk[wd][cidx] = src;
            s_w[wd][cidx]  = leaky02(as_[src] + s_ad[wd]);
          }
        }
      }
      __syncthreads();

      const int d0 = s_d[wid][0], d1 = s_d[wid][1], d2 = s_d[wid][2];
      const int sB = d0 + d1;
      const int deg = sB + d2;
      const float adn = s_ad[wid];
      float es = leaky02(as_[n] + adn);

      bool v1 = h < deg;
      bool v2 = h + 64 < deg;
      float e1 = v1 ? s_w[wid][h]      : -1e30f;
      float e2 = v2 ? s_w[wid][64 + h] : -1e30f;
      float mg = fmaxf(fmaxf(e1, e2), es);
      #pragma unroll
      for (int ofs = 1; ofs < 64; ofs <<= 1) mg = fmaxf(mg, __shfl_xor(mg, ofs));
      float w1 = v1 ? __expf(e1 - mg) : 0.f;
      float w2 = v2 ? __expf(e2 - mg) : 0.f;
      if (v1) s_w[wid][h] = w1;
      if (v2) s_w[wid][64 + h] = w2;
      float den = w1 + w2;
      #pragma unroll
      for (int ofs = 1; ofs < 64; ofs <<= 1) den += __shfl_xor(den, ofs);
      float wsf = __expf(es - mg);
      den += wsf;

      const float i0 = 1.f / (float)(d0 > 1 ? d0 : 1);
      const float i1 = 1.f / (float)(d1 > 1 ? d1 : 1);
      const float i2 = 1.f / (float)(d2 > 1 ? d2 : 1);
      const unsigned short* ybg = Ybg + (size_t)n * 384;
      const float b0p = bf2f(ybg[h])       * i0, g0p = bf2f(ybg[64 + h])  * i0;
      const float b1p = bf2f(ybg[128 + h]) * i1, g1p = bf2f(ybg[192 + h]) * i1;
      const float b2p = bf2f(ybg[256 + h]) * i2, g2p = bf2f(ybg[320 + h]) * i2;

      float S = wsf * bf2f(XP[(size_t)n * 64 + h]);
      float f = 0.f;

      int kA[4], kB[4], kD[4];
      #pragma unroll
      for (int k = 0; k < 4; k++) {
        kA[k] = s_d[k][0];
        kB[k] = kA[k] + s_d[k][1];
        kD[k] = kB[k] + s_d[k][2];
      }
      int dmax = max(max(kD[0], kD[1]), max(kD[2], kD[3]));
      int rounds = (dmax + RPN - 1) / RPN;

      for (int r = 0; r < rounds; r++) {
        int e0 = r * RPN;
        #pragma unroll
        for (int k = 0; k < 4; k++) {
          int jj = e0 + grp16;
          if (jj < kD[k]) {
            int src = s_pk[k][jj];
            int t = jj < kA[k] ? 0 : (jj < kB[k] ? 1 : 2);
            const unsigned short* row = (lane16 < 8)
                ? XP + (size_t)src * 64 + lane16 * 8
                : XR + ((size_t)t * NN + src) * 64 + (lane16 - 8) * 8;
            uint4 v = *reinterpret_cast<const uint4*>(row);
            *reinterpret_cast<uint4*>(&s_rows[16 * k + grp16][lane16 * 8]) = v;
          }
        }
        __syncthreads();
        const unsigned short* rowp = &s_rows[wid * RPN][0];
        int hi0 = min(e0 + RPN, d0);
        for (int i = e0; i < hi0; i++) {
          float wj = s_w[wid][i];
          int sr = i - e0;
          float xp = bf2f(rowp[sr * 128 + h]);
          float xr = bf2f(rowp[sr * 128 + 64 + h]);
          S += wj * xp;
          f += fmaxf(g0p * xr + b0p, 0.f);
        }
        int lo1 = max(e0, d0), hi1 = min(e0 + RPN, sB);
        for (int i = lo1; i < hi1; i++) {
          float wj = s_w[wid][i];
          int sr = i - e0;
          float xp = bf2f(rowp[sr * 128 + h]);
          float xr = bf2f(rowp[sr * 128 + 64 + h]);
          S += wj * xp;
          f += fmaxf(g1p * xr + b1p, 0.f);
        }
        int lo2 = max(e0, sB), hi2 = min(e0 + RPN, deg);
        for (int i = lo2; i < hi2; i++) {
          float wj = s_w[wid][i];
          int sr = i - e0;
          float xp = bf2f(rowp[sr * 128 + h]);
          float xr = bf2f(rowp[sr * 128 + 64 + h]);
          S += wj * xp;
          f += fmaxf(g2p * xr + b2p, 0.f);
        }
        __syncthreads();
      }

      float o1 = fmaxf(bf2f(S0b[(size_t)n * 64 + h]) + f, 0.f);
      float o2 = fmaxf(S / den + gat_b[h], 0.f);

      s_val[wid * 128 + h]      = o1;
      s_val[wid * 128 + 64 + h] = o2;
      if (h == 0) {
        int g = s_g[wid];
        if (n == 0 || gb[n - 1] != g)      gstart[g] = n;
        if (n == NN - 1 || gb[n + 1] != g) gend[g] = n;
      }
      __syncthreads();
      if (tid < 128) {
        int fch = tid;
        int curg = s_g[0];
        float v0 = s_val[fch];
        float mx = v0, sm = v0;
        #pragma unroll
        for (int j = 1; j < 4; j++) {
          float v = s_val[j * 128 + fch];
          if (s_g[j] == curg) { mx = fmaxf(mx, v); sm += v; }
          else {
            atomicMaxFPos(&pm[curg * 128 + fch], mx);
            atomicAdd(&ps[curg * 128 + fch], sm);
            curg = s_g[j]; mx = v; sm = v;
          }
        }
        atomicMaxFPos(&pm[curg * 128 + fch], mx);
        atomicAdd(&ps[curg * 128 + fch], sm);
      }
    }
  }
  __threadfence();
  grid.sync();

  // -------------------- phase 3: head (first 64 blocks) --------------------
  if (bid < GG) {
    float* p        = (float*)smem;               // 1024B
    float (*ph)[64] = (float(*)[64])(smem + 1024);// 1024B
    float* hid      = (float*)(smem + 2048);      // 256B
    float* lg       = (float*)(smem + 2304);      // 40B
    float* lsep     = (float*)(smem + 2352);
    int g = bid, t = tid;
    int s = gstart[g], e = gend[g];
    int cnt = (s <= e && s < NN && s >= 0) ? (e - s + 1) : 0;
    float invc = 1.f / (float)(cnt > 1 ? cnt : 1);
    if (t < 128) {
      float mx = 0.f;
      #pragma unroll
      for (int r = 0; r < RPL; r++)
        mx = fmaxf(mx, pmax[((size_t)r * GG + g) * 128 + t]);
      p[t] = mx;
    } else {
      int f = t - 128;
      float sm = 0.f;
      #pragma unroll
      for (int r = 0; r < RPL; r++)
        sm += psum[((size_t)r * GG + g) * 128 + f];
      p[t] = sm * invc;
    }
    __syncthreads();
    {
      int part = t >> 6, tt = t & 63;
      float acc = 0.f;
      int k0 = part * 64;
      for (int k = k0; k < k0 + 64; k++) acc += p[k] * lin_W[k * 64 + tt];
      ph[part][tt] = acc;
    }
    __syncthreads();
    if (t < 64) {
      float a = lin_b[t] + ph[0][t] + ph[1][t] + ph[2][t] + ph[3][t];
      hid[t] = fmaxf(a, 0.f);
    }
    __syncthreads();
    if (t < CC) {
      float a = fc_b[t];
      for (int k = 0; k < 64; k++) a += hid[k] * fc_W[k * CC + t];
      lg[t] = a;
    }
    __syncthreads();
    if (t == 0) {
      float mx = lg[0];
      for (int i = 1; i < CC; i++) mx = fmaxf(mx, lg[i]);
      float sum = 0.f;
      for (int i = 0; i < CC; i++) sum += expf(lg[i] - mx);
      *lsep = mx + logf(sum);
    }
    __syncthreads();
    if (t < CC) out[g * CC + t] = lg[t] - *lsep;
  }
}

// ===================== fallback path (r21, 4 launches) ====================
__global__ void wpack_k(const float* __restrict__ skip_film_W,
                        const float* __restrict__ skip_W,
                        const float* __restrict__ film_lin_W,
                        const float* __restrict__ film_film_W,
                        const float* __restrict__ gat_W,
                        const float* __restrict__ skip_film_b,
                        const float* __restrict__ film_film_b,
                        unsigned short* __restrict__ Wt,
                        float* __restrict__ bias,
                        float* __restrict__ zbase, int zN4) {
  int tid0 = blockIdx.x * 256 + threadIdx.x;
  float4 z4 = {0.f, 0.f, 0.f, 0.f};
  for (int i = tid0; i < zN4; i += gridDim.x * 256)
    reinterpret_cast<float4*>(zbase)[i] = z4;
  int idx = tid0;
  if (idx >= WTN) return;
  if (idx >= 832 * 64) {
    int c = idx - 832 * 64;
    float bv = 0.f;
    if (c < 128) bv = skip_film_b[c];
    else if (c >= 384 && c < 768) bv = film_film_b[c - 384];
    bias[c] = bv;
    return;
  }
  Wt[idx] = f2bf(wpack_val(idx, skip_film_W, skip_W, film_lin_W,
                           film_film_W, gat_W));
}

__global__ __launch_bounds__(256) void fuse_k(const float* __restrict__ X,
    const unsigned short* __restrict__ Wt, const float* __restrict__ bias,
    const float* __restrict__ att_src, const float* __restrict__ att_dst,
    unsigned short* __restrict__ XP, unsigned short* __restrict__ XR,
    unsigned short* __restrict__ Ybg,
    unsigned short* __restrict__ S0b, float* __restrict__ as_,
    float* __restrict__ ad_,
    const int* __restrict__ ei, const int* __restrict__ et,
    int* __restrict__ fill4, unsigned short* __restrict__ sorted) {
  __shared__ __align__(16) unsigned short As[64][72];
  __shared__ __align__(16) unsigned short Bs[128][72];
  const int tid = threadIdx.x;
  const int bid = blockIdx.x;

  if (bid % 3 != 0) {
    int sb = bid - bid / 3 - 1;
    int e = sb * 512 + tid * 2;
    if (e < EE) {
      int2 s2 = *reinterpret_cast<const int2*>(ei + e);
      int2 d2 = *reinterpret_cast<const int2*>(ei + EE + e);
      int2 t2 = *reinterpret_cast<const int2*>(et + e);
      int slot = atomicAdd(&fill4[d2.x * 4 + t2.x], 1);
      if (slot < 32)
        sorted[(size_t)d2.x * 96 + t2.x * 32 + slot] = (unsigned short)s2.x;
      slot = atomicAdd(&fill4[d2.y * 4 + t2.y], 1);
      if (slot < 32)
        sorted[(size_t)d2.y * 96 + t2.y * 32 + slot] = (unsigned short)s2.y;
    }
    return;
  }

  const int row0 = (bid / 3) * 64;
  {
    int r = tid >> 2, c0 = (tid & 3) * 16;
    int gr = row0 + r;
    ushort4 o0 = {0,0,0,0}, o1 = {0,0,0,0}, o2 = {0,0,0,0}, o3 = {0,0,0,0};
    if (gr < NN) {
      const float4* p = reinterpret_cast<const float4*>(X + (size_t)gr * 64 + c0);
      float4 v0 = p[0], v1 = p[1], v2 = p[2], v3 = p[3];
      o0 = {f2bf(v0.x), f2bf(v0.y), f2bf(v0.z), f2bf(v0.w)};
      o1 = {f2bf(v1.x), f2bf(v1.y), f2bf(v1.z), f2bf(v1.w)};
      o2 = {f2bf(v2.x), f2bf(v2.y), f2bf(v2.z), f2bf(v2.w)};
      o3 = {f2bf(v3.x), f2bf(v3.y), f2bf(v3.z), f2bf(v3.w)};
    }
    *reinterpret_cast<ushort4*>(&As[r][c0])      = o0;
    *reinterpret_cast<ushort4*>(&As[r][c0 + 4])  = o1;
    *reinterpret_cast<ushort4*>(&As[r][c0 + 8])  = o2;
    *reinterpret_cast<ushort4*>(&As[r][c0 + 12]) = o3;
  }
  __syncthreads();

  const int w = tid >> 6, lane = tid & 63;
  const int m = lane & 15, q = lane >> 4;
  bf16x8 a0 = *reinterpret_cast<const bf16x8*>(&As[16 * w + m][q * 8]);
  bf16x8 a1 = *reinterpret_cast<const bf16x8*>(&As[16 * w + m][32 + q * 8]);
  const int rbase = row0 + 16 * w + q * 4;

  f32x4 t0[8], t1[4], t6[4];

  for (int tile = 0; tile < 7; tile++) {
    __syncthreads();
    int col0 = tile * 128;
    int width = (tile == 6) ? 64 : 128;
    {
      int c = tid >> 1, half = (tid & 1) * 32;
      if (c < width) {
        int gc = col0 + c;
        const uint4* p = reinterpret_cast<const uint4*>(Wt + (size_t)gc * 64 + half);
        uint4 v0 = p[0], v1 = p[1], v2 = p[2], v3 = p[3];
        *reinterpret_cast<uint4*>(&Bs[c][half])      = v0;
        *reinterpret_cast<uint4*>(&Bs[c][half + 8])  = v1;
        *reinterpret_cast<uint4*>(&Bs[c][half + 16]) = v2;
        *reinterpret_cast<uint4*>(&Bs[c][half + 24]) = v3;
      }
    }
    __syncthreads();
    #pragma unroll
    for (int ct = 0; ct < 8; ct++) {
      if (tile == 6 && ct >= 4) continue;
      bf16x8 b0 = *reinterpret_cast<const bf16x8*>(&Bs[ct * 16 + m][q * 8]);
      bf16x8 b1 = *reinterpret_cast<const bf16x8*>(&Bs[ct * 16 + m][32 + q * 8]);
      f32x4 acc = {0.f, 0.f, 0.f, 0.f};
      acc = __builtin_amdgcn_mfma_f32_16x16x32_bf16(a0, b0, acc, 0, 0, 0);
      acc = __builtin_amdgcn_mfma_f32_16x16x32_bf16(a1, b1, acc, 0, 0, 0);
      if (tile == 0) { t0[ct] = acc; continue; }
      if (tile == 1 && ct < 4) { t1[ct] = acc; continue; }
      if (tile == 6) t6[ct] = acc;
      int colm = ct * 16 + m;
      float bv = (tile >= 3 && tile <= 5) ? bias[col0 + colm] : 0.f;
      #pragma unroll
      for (int rg = 0; rg < 4; rg++) {
        int gr = rbase + rg;
        if (gr >= NN) continue;
        float v = acc[rg];
        if (tile == 1) {
          XR[(size_t)gr * 64 + (colm - 64)] = f2bf(v);
        } else if (tile == 2) {
          if (ct < 4) XR[((size_t)NN + gr) * 64 + colm]            = f2bf(v);
          else        XR[((size_t)2 * NN + gr) * 64 + (colm - 64)] = f2bf(v);
        } else if (tile <= 5) {
          Ybg[(size_t)gr * 384 + (col0 - 384) + colm] = f2bf(v + bv);
        } else {
          XP[(size_t)gr * 64 + colm] = f2bf(v);
        }
      }
    }
  }

  float pa[4] = {0.f, 0.f, 0.f, 0.f}, pd[4] = {0.f, 0.f, 0.f, 0.f};
  #pragma unroll
  for (int j = 0; j < 4; j++) {
    int h = 16 * j + m;
    float bb = bias[h];
    float bg = bias[64 + h];
    float asv = att_src[h];
    float adv = att_dst[h];
    #pragma unroll
    for (int rg = 0; rg < 4; rg++) {
      float so = fmaxf((t0[4 + j][rg] + bg) * t1[j][rg] + (t0[j][rg] + bb), 0.f);
      int gr = rbase + rg;
      if (gr < NN) S0b[(size_t)gr * 64 + h] = f2bf(so);
      pa[rg] += t6[j][rg] * asv;
      pd[rg] += t6[j][rg] * adv;
    }
  }
  #pragma unroll
  for (int ofs = 1; ofs < 16; ofs <<= 1) {
    #pragma unroll
    for (int rg = 0; rg < 4; rg++) {
      pa[rg] += __shfl_xor(pa[rg], ofs);
      pd[rg] += __shfl_xor(pd[rg], ofs);
    }
  }
  if (m == 0) {
    #pragma unroll
    for (int rg = 0; rg < 4; rg++) {
      int gr = rbase + rg;
      if (gr < NN) { as_[gr] = pa[rg]; ad_[gr] = pd[rg]; }
    }
  }
}

__global__ __launch_bounds__(256) void dst_k(const unsigned short* __restrict__ sorted,
    const int* __restrict__ fill4, const unsigned short* __restrict__ XP,
    const unsigned short* __restrict__ XR,
    const unsigned short* __restrict__ Ybg,
    const unsigned short* __restrict__ S0b,
    const float* __restrict__ as_, const float* __restrict__ ad_,
    const float* __restrict__ gat_b, const int* __restrict__ gb,
    float* __restrict__ pmax, float* __restrict__ psum,
    int* __restrict__ gstart, int* __restrict__ gend) {
  __shared__ int   s_pk[4][96];
  __shared__ float s_w [4][96];
  __shared__ int   s_d [4][4];
  __shared__ int s_g[4];
  __shared__ float s_ad[4];
  __shared__ __align__(16) unsigned short s_rows[64][128];
  float* s_val = (float*)&s_rows[0][0];

  const int tid = threadIdx.x;
  const int wid = tid >> 6, h = tid & 63;
  const int n0 = blockIdx.x * 4;
  const int n  = n0 + wid;

  size_t rep = (size_t)(blockIdx.x & (RPL - 1)) * GG * 128;
  pmax += rep; psum += rep;

  if (tid < 16) {
    int wd = tid >> 2, t = tid & 3;
    if (t < 3) {
      int d = fill4[(n0 + wd) * 4 + t];
      s_d[wd][t] = d > 32 ? 32 : d;
    } else {
      s_g[wd]  = gb[n0 + wd];
      s_ad[wd] = ad_[n0 + wd];
    }
  }
  __syncthreads();

  for (int i = tid; i < 512; i += 256) {
    int wd = i >> 7, s = i & 127;
    if (s < 96) {
      int tt = s >> 5, j = s & 31;
      if (j < s_d[wd][tt]) {
        int cidx = (tt == 0) ? j
                 : (tt == 1) ? s_d[wd][0] + j
                             : s_d[wd][0] + s_d[wd][1] + j;
        int src = sorted[(size_t)(n0 + wd) * 96 + s];
        s_pk[wd][cidx] = src;
        s_w[wd][cidx]  = leaky02(as_[src] + s_ad[wd]);
      }
    }
  }
  __syncthreads();

  const int d0 = s_d[wid][0], d1 = s_d[wid][1], d2 = s_d[wid][2];
  const int sB = d0 + d1;
  const int deg = sB + d2;
  const float adn = s_ad[wid];
  float es = leaky02(as_[n] + adn);

  bool v1 = h < deg;
  bool v2 = h + 64 < deg;
  float e1 = v1 ? s_w[wid][h]      : -1e30f;
  float e2 = v2 ? s_w[wid][64 + h] : -1e30f;
  float mg = fmaxf(fmaxf(e1, e2), es);
  #pragma unroll
  for (int ofs = 1; ofs < 64; ofs <<= 1) mg = fmaxf(mg, __shfl_xor(mg, ofs));
  float w1 = v1 ? __expf(e1 - mg) : 0.f;
  float w2 = v2 ? __expf(e2 - mg) : 0.f;
  if (v1) s_w[wid][h] = w1;
  if (v2) s_w[wid][64 + h] = w2;
  float den = w1 + w2;
  #pragma unroll
  for (int ofs = 1; ofs < 64; ofs <<= 1) den += __shfl_xor(den, ofs);
  float ws = __expf(es - mg);
  den += ws;

  const float i0 = 1.f / (float)(d0 > 1 ? d0 : 1);
  const float i1 = 1.f / (float)(d1 > 1 ? d1 : 1);
  const float i2 = 1.f / (float)(d2 > 1 ? d2 : 1);
  const unsigned short* ybg = Ybg + (size_t)n * 384;
  const float b0p = bf2f(ybg[h])       * i0, g0p = bf2f(ybg[64 + h])  * i0;
  const float b1p = bf2f(ybg[128 + h]) * i1, g1p = bf2f(ybg[192 + h]) * i1;
  const float b2p = bf2f(ybg[256 + h]) * i2, g2p = bf2f(ybg[320 + h]) * i2;

  float S = ws * bf2f(XP[(size_t)n * 64 + h]);
  float f = 0.f;

  const int grp16 = tid >> 4, lane16 = tid & 15;
  int kA[4], kB[4], kD[4];
  #pragma unroll
  for (int k = 0; k < 4; k++) {
    kA[k] = s_d[k][0];
    kB[k] = kA[k] + s_d[k][1];
    kD[k] = kB[k] + s_d[k][2];
  }
  int dmax = max(max(kD[0], kD[1]), max(kD[2], kD[3]));
  int rounds = (dmax + RPN - 1) / RPN;

  for (int r = 0; r < rounds; r++) {
    int e0 = r * RPN;
    #pragma unroll
    for (int k = 0; k < 4; k++) {
      int jj = e0 + grp16;
      if (jj < kD[k]) {
        int src = s_pk[k][jj];
        int t = jj < kA[k] ? 0 : (jj < kB[k] ? 1 : 2);
        const unsigned short* row = (lane16 < 8)
            ? XP + (size_t)src * 64 + lane16 * 8
            : XR + ((size_t)t * NN + src) * 64 + (lane16 - 8) * 8;
        uint4 v = *reinterpret_cast<const uint4*>(row);
        *reinterpret_cast<uint4*>(&s_rows[16 * k + grp16][lane16 * 8]) = v;
      }
    }
    __syncthreads();
    const unsigned short* rowp = &s_rows[wid * RPN][0];
    int hi0 = min(e0 + RPN, d0);
    for (int i = e0; i < hi0; i++) {
      float wj = s_w[wid][i];
      int sr = i - e0;
      float xp = bf2f(rowp[sr * 128 + h]);
      float xr = bf2f(rowp[sr * 128 + 64 + h]);
      S += wj * xp;
      f += fmaxf(g0p * xr + b0p, 0.f);
    }
    int lo1 = max(e0, d0), hi1 = min(e0 + RPN, sB);
    for (int i = lo1; i < hi1; i++) {
      float wj = s_w[wid][i];
      int sr = i - e0;
      float xp = bf2f(rowp[sr * 128 + h]);
      float xr = bf2f(rowp[sr * 128 + 64 + h]);
      S += wj * xp;
      f += fmaxf(g1p * xr + b1p, 0.f);
    }
    int lo2 = max(e0, sB), hi2 = min(e0 + RPN, deg);
    for (int i = lo2; i < hi2; i++) {
      float wj = s_w[wid][i];
      int sr = i - e0;
      float xp = bf2f(rowp[sr * 128 + h]);
      float xr = bf2f(rowp[sr * 128 + 64 + h]);
      S += wj * xp;
      f += fmaxf(g2p * xr + b2p, 0.f);
    }
    __syncthreads();
  }

  float o1 = fmaxf(bf2f(S0b[(size_t)n * 64 + h]) + f, 0.f);
  float o2 = fmaxf(S / den + gat_b[h], 0.f);

  s_val[wid * 128 + h]      = o1;
  s_val[wid * 128 + 64 + h] = o2;
  if (h == 0) {
    int g = s_g[wid];
    if (n == 0 || gb[n - 1] != g)      gstart[g] = n;
    if (n == NN - 1 || gb[n + 1] != g) gend[g] = n;
  }
  __syncthreads();
  if (tid < 128) {
    int fch = tid;
    int curg = s_g[0];
    float v0 = s_val[fch];
    float mx = v0, sm = v0;
    #pragma unroll
    for (int j = 1; j < 4; j++) {
      float v = s_val[j * 128 + fch];
      if (s_g[j] == curg) { mx = fmaxf(mx, v); sm += v; }
      else {
        atomicMaxFPos(&pmax[curg * 128 + fch], mx);
        atomicAdd(&psum[curg * 128 + fch], sm);
        curg = s_g[j]; mx = v; sm = v;
      }
    }
    atomicMaxFPos(&pmax[curg * 128 + fch], mx);
    atomicAdd(&psum[curg * 128 + fch], sm);
  }
}

__global__ __launch_bounds__(256) void head_k(const float* __restrict__ pmax,
    const float* __restrict__ psum, const int* __restrict__ gstart,
    const int* __restrict__ gend,
    const float* __restrict__ lin_W, const float* __restrict__ lin_b,
    const float* __restrict__ fc_W, const float* __restrict__ fc_b,
    float* __restrict__ out) {
  __shared__ float p[256];
  __shared__ float ph[4][64];
  __shared__ float hid[64];
  __shared__ float lg[CC];
  __shared__ float lse;
  int g = blockIdx.x, t = threadIdx.x;
  int s = gstart[g], e = gend[g];
  int cnt = (s <= e && s < NN && s >= 0) ? (e - s + 1) : 0;
  float invc = 1.f / (float)(cnt > 1 ? cnt : 1);
  if (t < 128) {
    float mx = 0.f;
    #pragma unroll
    for (int r = 0; r < RPL; r++)
      mx = fmaxf(mx, pmax[((size_t)r * GG + g) * 128 + t]);
    p[t] = mx;
  } else {
    int f = t - 128;
    float sm = 0.f;
    #pragma unroll
    for (int r = 0; r < RPL; r++)
      sm += psum[((size_t)r * GG + g) * 128 + f];
    p[t] = sm * invc;
  }
  __syncthreads();
  {
    int part = t >> 6, tt = t & 63;
    float acc = 0.f;
    int k0 = part * 64;
    for (int k = k0; k < k0 + 64; k++) acc += p[k] * lin_W[k * 64 + tt];
    ph[part][tt] = acc;
  }
  __syncthreads();
  if (t < 64) {
    float a = lin_b[t] + ph[0][t] + ph[1][t] + ph[2][t] + ph[3][t];
    hid[t] = fmaxf(a, 0.f);
  }
  __syncthreads();
  if (t < CC) {
    float a = fc_b[t];
    for (int k = 0; k < 64; k++) a += hid[k] * fc_W[k * CC + t];
    lg[t] = a;
  }
  __syncthreads();
  if (t == 0) {
    float mx = lg[0];
    for (int i = 1; i < CC; i++) mx = fmaxf(mx, lg[i]);
    float sum = 0.f;
    for (int i = 0; i < CC; i++) sum += expf(lg[i] - mx);
    lse = mx + logf(sum);
  }
  __syncthreads();
  if (t < CC) out[g * CC + t] = lg[t] - lse;
}

extern "C" void kernel_launch(void* const* d_in, const int* in_sizes, int n_in,
                              void* d_out, int out_size, void* d_ws, size_t ws_size,
                              hipStream_t stream) {
  const float* x            = (const float*)d_in[0];
  const int*   edge_index   = (const int*)d_in[1];
  const int*   edge_type    = (const int*)d_in[2];
  const int*   graph_batch  = (const int*)d_in[3];
  const float* film_lin_W   = (const float*)d_in[4];
  const float* film_film_W  = (const float*)d_in[5];
  const float* film_film_b  = (const float*)d_in[6];
  const float* skip_W       = (const float*)d_in[7];
  const float* skip_film_W  = (const float*)d_in[8];
  const float* skip_film_b  = (const float*)d_in[9];
  const float* gat_W        = (const float*)d_in[10];
  const float* att_src      = (const float*)d_in[11];
  const float* att_dst      = (const float*)d_in[12];
  const float* gat_b        = (const float*)d_in[13];
  const float* lin_W        = (const float*)d_in[14];
  const float* lin_b        = (const float*)d_in[15];
  const float* fc_W         = (const float*)d_in[16];
  const float* fc_b         = (const float*)d_in[17];
  float* out                = (float*)d_out;

  float* ws = (float*)d_ws;
  const size_t N = NN, G = GG;
  size_t oXP     = 0;
  size_t oXR     = N * 32;
  size_t oYbg    = oXR + N * 96;
  size_t oS0     = oYbg + N * 192;
  size_t oAs     = oS0 + N * 32;
  size_t oAd     = oAs + N;
  size_t oWt     = oAd + N;
  size_t oBias   = oWt + 832 * 32;
  size_t oPmax   = oBias + 832;
  size_t oPsum   = oPmax + (size_t)RPL * G * 128;
  size_t oGend   = oPsum + (size_t)RPL * G * 128;
  size_t oFill   = oGend + G;
  size_t oGstart = oFill + N * 4;
  size_t oSorted = oGstart + G;            // N*96 u16

  unsigned short* XP  = (unsigned short*)(ws + oXP);
  unsigned short* XR  = (unsigned short*)(ws + oXR);
  unsigned short* Ybg = (unsigned short*)(ws + oYbg);
  unsigned short* S0b = (unsigned short*)(ws + oS0);
  float* as_    = ws + oAs;
  float* ad_    = ws + oAd;
  unsigned short* Wt  = (unsigned short*)(ws + oWt);
  float* bias   = ws + oBias;
  float* pmax   = ws + oPmax;
  float* psum   = ws + oPsum;
  int*   gend   = (int*)(ws + oGend);
  int*   fill4  = (int*)(ws + oFill);
  int*   gstart = (int*)(ws + oGstart);
  unsigned short* sorted = (unsigned short*)(ws + oSorted);

  float* zbase = pmax;
  int zN4 = (int)((oGstart - oPmax) / 4);   // pmax,psum,gend,fill4 (float4s)

  static int s_mode = 0;     // 0 = undecided, 1 = cooperative, 2 = fallback
  static int s_nblk = 0;
  if (s_mode == 0) {
    int bpc = 0;
    hipError_t oe = hipOccupancyMaxActiveBlocksPerMultiprocessor(
        &bpc, reinterpret_cast<const void*>(mega_k), 256, 0);
    if (oe == hipSuccess && bpc >= 1) {
      s_nblk = bpc * 256;                 // 256 CUs on MI355X
      if (s_nblk > 2048) s_nblk = 2048;
      s_mode = 1;
    } else {
      s_mode = 2;
    }
  }

  if (s_mode == 1) {
    void* args[] = {
      (void*)&x, (void*)&edge_index, (void*)&edge_type, (void*)&graph_batch,
      (void*)&skip_film_W, (void*)&skip_W, (void*)&film_lin_W,
      (void*)&film_film_W, (void*)&gat_W, (void*)&skip_film_b,
      (void*)&film_film_b, (void*)&att_src, (void*)&att_dst, (void*)&gat_b,
      (void*)&lin_W, (void*)&lin_b, (void*)&fc_W, (void*)&fc_b,
      (void*)&XP, (void*)&XR, (void*)&Ybg, (void*)&S0b, (void*)&as_,
      (void*)&ad_, (void*)&Wt, (void*)&bias, (void*)&pmax, (void*)&psum,
      (void*)&gend, (void*)&fill4, (void*)&gstart, (void*)&sorted,
      (void*)&zbase, (void*)&zN4, (void*)&out
    };
    hipError_t le = hipLaunchCooperativeKernel(
        reinterpret_cast<void*>(mega_k), dim3(s_nblk), dim3(256),
        args, 0, stream);
    if (le == hipSuccess) return;
    s_mode = 2;                           // fall through to 4-launch path
  }

  // -------- fallback: r21 four-launch pipeline --------
  wpack_k<<<212, 256, 0, stream>>>(skip_film_W, skip_W, film_lin_W,
                                   film_film_W, gat_W, skip_film_b,
                                   film_film_b, Wt, bias, zbase, zN4);
  fuse_k<<<NBG + NBS, 256, 0, stream>>>(x, Wt, bias, att_src, att_dst,
                                        XP, XR, Ybg, S0b, as_, ad_,
                                        edge_index, edge_type, fill4, sorted);
  dst_k<<<NN / 4, 256, 0, stream>>>(sorted, fill4, XP, XR, Ybg, S0b, as_, ad_,
                                    gat_b, graph_batch, pmax, psum,
                                    gstart, gend);
  head_k<<<GG, 256, 0, stream>>>(pmax, psum, gstart, gend,
                                 lin_W, lin_b, fc_W, fc_b, out);
}